// Round 5
// baseline (136.539 us; speedup 1.0000x reference)
//
#include <hip/hip_runtime.h>
#include <hip/hip_bf16.h>
#include <cstdint>
#include <cstddef>

// Problem constants
constexpr int NB = 32;     // batch
constexpr int NH = 16;     // heads
constexpr int NS = 8192;   // seq len
constexpr int NK = 2048;   // top-k
constexpr int NL = 512;    // latent dim
constexpr int NDR = 64;    // rope dim
constexpr int NDV = 128;   // v head dim
constexpr int NDM = 2048;  // model dim
constexpr int NDN = 128;   // nope dim
constexpr float SCALE = 0.07216878364870322f; // 1/sqrt(192)

constexpr int NSPLIT = 16;      // k-splits (blocks per batch)
constexpr int KC = NK / NSPLIT; // 128 k per block
constexpr int KT = 32;          // rows per subtile
constexpr int NT = KC / KT;     // 4 subtiles per block
constexpr int ND = NL + NDR;    // 576 staged dims
constexpr int NSUB_D = ND / 16; // 36 subtiles per 4-row group
constexpr int NS2 = 32;         // n-splits for final GEMM

typedef __attribute__((ext_vector_type(8))) short sh8;
typedef __attribute__((ext_vector_type(4))) float f32x4;

__device__ __forceinline__ short bf16c(float f) {
  union { float f; uint32_t u; } v; v.f = f;
  uint32_t r = v.u + 0x7fffu + ((v.u >> 16) & 1u);
  return (short)(r >> 16);
}

__device__ __forceinline__ float bf2f(short s) {
  union { uint32_t u; float f; } v; v.u = ((uint32_t)(uint16_t)s) << 16;
  return v.f;
}

__device__ __forceinline__ sh8 pack_bf8(float4 a, float4 b) {
  sh8 f;
  f[0] = bf16c(a.x); f[1] = bf16c(a.y); f[2] = bf16c(a.z); f[3] = bf16c(a.w);
  f[4] = bf16c(b.x); f[5] = bf16c(b.y); f[6] = bf16c(b.z); f[7] = bf16c(b.w);
  return f;
}

// swizzled element index within the subtiled KV layout (shorts).
// element (k,d): s = (k>>2)*NSUB_D + (d>>4), e = (k&3)*16 + (d&15)
__device__ __forceinline__ int swz(int s, int e) {
  return s * 64 + (e ^ (((s ^ (s >> 3)) & 7) << 3));
}

// ---------------- Kernel 1: qle[b,h,0:512] = bf16(q_nope . W_UK), [512:576] = bf16(q_pe)
__global__ void k_qprep(const float* __restrict__ qn,
                        const float* __restrict__ qpe,
                        const float* __restrict__ wuk,
                        short* __restrict__ qle) {
  int bh = blockIdx.x;
  int h = bh & (NH - 1);
  __shared__ float q[NDN];
  int t = threadIdx.x;
  if (t < NDN) q[t] = qn[(size_t)bh * NDN + t];
  __syncthreads();
  for (int l = t; l < NL; l += 256) {
    const float4* wr = (const float4*)&wuk[((size_t)l * NH + h) * NDN];
    float acc = 0.f;
    #pragma unroll
    for (int j = 0; j < NDN / 4; ++j) {
      float4 wv = wr[j];
      float4 qv = *(const float4*)&q[j * 4];
      acc += wv.x * qv.x + wv.y * qv.y + wv.z * qv.z + wv.w * qv.w;
    }
    qle[(size_t)bh * ND + l] = bf16c(acc);
  }
  if (t < NDR) qle[(size_t)bh * ND + NL + t] = bf16c(qpe[(size_t)bh * NDR + t]);
}

// ---------------- Kernel 2: streaming-flash MFMA attention partial per (split, b)
__global__ __launch_bounds__(256, 2)
void k_attn(const float* __restrict__ kvc,
            const float* __restrict__ kpe,
            const int*   __restrict__ topk,
            const short* __restrict__ qle,
            float* __restrict__ pm,
            float* __restrict__ psum,
            unsigned short* __restrict__ po) {
  const int sp = blockIdx.x;     // 0..NSPLIT-1
  const int b  = blockIdx.y;     // 0..NB-1
  const int t  = threadIdx.x;
  const int w  = t >> 6;         // wave 0..3
  const int lane = t & 63;
  const int lg = lane >> 4;      // lane group 0..3
  const int ln = lane & 15;

  __shared__ __align__(16) short kvs[2][(KT / 4) * NSUB_D * 64]; // 2 x 36864 B
  __shared__ __align__(16) short plds[NH * 40];                  // P bf16
  __shared__ float mlds[32], slds[32];
  __shared__ float mrun[16], srun[16], elds[16], mnewl[16];
  __shared__ int idxl[KC];

  if (t < KC) idxl[t] = topk[(size_t)b * NK + sp * KC + t];
  if (t < 16) { mrun[t] = -1e30f; srun[t] = 0.f; }
  __syncthreads();

  const int r = t >> 3, c8 = t & 7;   // staging: row r (0..31), 8-float col group c8
  float4 va[9], vb[9];

  auto LOADT = [&](int tile) {
    int idx = idxl[tile * KT + r];
    int id = idx < 0 ? 0 : (idx >= NS ? NS - 1 : idx);
    const float* rowc = kvc + ((size_t)b * NS + id) * NL;
    const float* rowp = kpe + ((size_t)b * NS + id) * NDR;
    #pragma unroll
    for (int i = 0; i < 8; ++i) {
      const float* src = rowc + c8 * 8 + i * 64;
      va[i] = *(const float4*)src;
      vb[i] = *(const float4*)(src + 4);
    }
    const float* srp = rowp + c8 * 8;
    va[8] = *(const float4*)srp;
    vb[8] = *(const float4*)(srp + 4);
  };
  auto WRITET = [&](int buf) {
    #pragma unroll
    for (int i = 0; i < 9; ++i) {
      int d0 = (i < 8) ? (c8 * 8 + i * 64) : (NL + c8 * 8);
      int s = (r >> 2) * NSUB_D + (d0 >> 4);
      int e = (r & 3) * 16 + (d0 & 15);
      *(sh8*)&kvs[buf][swz(s, e)] = pack_bf8(va[i], vb[i]);
    }
  };

  // prologue: tile0 -> buf0; tile1 loads in flight
  LOADT(0);
  WRITET(0);
  LOADT(1);
  __syncthreads();

  f32x4 acco[8];
  #pragma unroll
  for (int nt = 0; nt < 8; ++nt) acco[nt] = {0.f, 0.f, 0.f, 0.f};
  float sv[4];

  for (int it = 0; it < NT; ++it) {
    const int cur = it & 1;
    // -------- Phase A: QK (waves 0-1) || stage next tile (waves 2-3)
    if (w < 2) {
      const short* qrow = qle + ((size_t)b * NH + ln) * ND;
      int k = w * 16 + ln;
      f32x4 accs = {0.f, 0.f, 0.f, 0.f};
      #pragma unroll
      for (int kk = 0; kk < 18; ++kk) {
        int d0 = kk * 32 + lg * 8;
        sh8 qv = *(const sh8*)&qrow[d0];
        int s = (k >> 2) * NSUB_D + (d0 >> 4);
        int e = (k & 3) * 16 + (d0 & 15);
        sh8 bfr = *(const sh8*)&kvs[cur][swz(s, e)];
        accs = __builtin_amdgcn_mfma_f32_16x16x32_bf16(qv, bfr, accs, 0, 0, 0);
      }
      bool valid = idxl[it * KT + k] >= 0;
      float mx[4];
      #pragma unroll
      for (int q = 0; q < 4; ++q) {
        sv[q] = valid ? accs[q] * SCALE : -INFINITY;
        mx[q] = sv[q];
      }
      #pragma unroll
      for (int off = 1; off < 16; off <<= 1)
        #pragma unroll
        for (int q = 0; q < 4; ++q) mx[q] = fmaxf(mx[q], __shfl_xor(mx[q], off));
      if (ln == 0) {
        #pragma unroll
        for (int q = 0; q < 4; ++q) mlds[w * 16 + lg * 4 + q] = mx[q];
      }
    } else {
      if (it < NT - 1) WRITET(cur ^ 1);
      if (it < NT - 2) LOADT(it + 2);
    }
    __syncthreads();  // S1
    // -------- Phase B: running-max update
    if (t < 16) {
      float mt = fmaxf(mlds[t], mlds[16 + t]);
      float mn = fmaxf(mrun[t], mt);
      elds[t] = __expf(mrun[t] - mn);
      mnewl[t] = mn;
      mrun[t] = mn;
    }
    __syncthreads();  // S2
    // -------- Phase C: P + partial sums (waves 0-1, then stage) ; all: rescale O
    if (w < 2) {
      float p[4], ss[4];
      #pragma unroll
      for (int q = 0; q < 4; ++q) {
        p[q] = __expf(sv[q] - mnewl[lg * 4 + q]);
        ss[q] = p[q];
      }
      #pragma unroll
      for (int off = 1; off < 16; off <<= 1)
        #pragma unroll
        for (int q = 0; q < 4; ++q) ss[q] += __shfl_xor(ss[q], off);
      if (ln == 0) {
        #pragma unroll
        for (int q = 0; q < 4; ++q) slds[w * 16 + lg * 4 + q] = ss[q];
      }
      #pragma unroll
      for (int q = 0; q < 4; ++q)
        plds[(lg * 4 + q) * 40 + w * 16 + ln] = bf16c(p[q]);
      if (it < NT - 1) WRITET(cur ^ 1);
      if (it < NT - 2) LOADT(it + 2);
    }
    {
      float eh[4];
      #pragma unroll
      for (int q = 0; q < 4; ++q) eh[q] = elds[lg * 4 + q];
      #pragma unroll
      for (int nt = 0; nt < 8; ++nt)
        #pragma unroll
        for (int q = 0; q < 4; ++q) acco[nt][q] *= eh[q];
    }
    __syncthreads();  // S3
    // -------- Phase D: running-sum update + PV (all waves)
    if (t < 16) srun[t] = srun[t] * elds[t] + slds[t] + slds[16 + t];
    {
      sh8 pa = *(const sh8*)&plds[ln * 40 + lg * 8];  // P[h=ln][k=lg*8+j]
      #pragma unroll
      for (int nt = 0; nt < 8; ++nt) {
        int l0 = w * 128 + nt * 16;
        sh8 bv;
        #pragma unroll
        for (int j = 0; j < 8; ++j) {
          int kj = lg * 8 + j;
          int s = (kj >> 2) * NSUB_D + (l0 >> 4);
          int e = (kj & 3) * 16 + ln;
          bv[j] = kvs[cur][swz(s, e)];
        }
        acco[nt] = __builtin_amdgcn_mfma_f32_16x16x32_bf16(pa, bv, acco[nt], 0, 0, 0);
      }
    }
    __syncthreads();  // S4: PV done reading kvs[cur] before next iter overwrites it
  }

  // -------- epilogue
  if (t < 16) {
    pm[((size_t)b * NSPLIT + sp) * NH + t] = mrun[t];
    psum[((size_t)b * NSPLIT + sp) * NH + t] = srun[t];
  }
  unsigned short* dst = po + (((size_t)b * NSPLIT + sp) * NH) * NL;
  #pragma unroll
  for (int nt = 0; nt < 8; ++nt) {
    int l = w * 128 + nt * 16 + ln;
    #pragma unroll
    for (int q = 0; q < 4; ++q)
      dst[(size_t)(lg * 4 + q) * NL + l] = (unsigned short)bf16c(acco[nt][q]);
  }
}

// ---------------- Kernel 3: combine splits, project with W_UV -> ov[b, h*DV + v]
__global__ void k_combine(const float* __restrict__ pm,
                          const float* __restrict__ psum,
                          const unsigned short* __restrict__ po,
                          const float* __restrict__ wuv,
                          float* __restrict__ ov) {
  int bh = blockIdx.x;
  int b = bh >> 4, h = bh & 15;
  __shared__ float coef[NSPLIT];
  __shared__ float ol[NL];
  __shared__ float red[2][NDV];
  int t = threadIdx.x;
  if (t < NSPLIT) {
    float m = pm[((size_t)b * NSPLIT + t) * NH + h];
    float M = m;
    #pragma unroll
    for (int off = 8; off; off >>= 1) M = fmaxf(M, __shfl_xor(M, off, 16));
    float term = psum[((size_t)b * NSPLIT + t) * NH + h] * __expf(m - M);
    float S = term;
    #pragma unroll
    for (int off = 8; off; off >>= 1) S += __shfl_xor(S, off, 16);
    coef[t] = __expf(m - M) / fmaxf(S, 1e-30f);
  }
  __syncthreads();
  for (int l = t; l < NL; l += 256) {
    float a = 0.f;
    #pragma unroll
    for (int i = 0; i < NSPLIT; ++i)
      a += coef[i] * bf2f((short)po[(((size_t)b * NSPLIT + i) * NH + h) * NL + l]);
    ol[l] = a;
  }
  __syncthreads();
  {
    int v = t & (NDV - 1);
    int half = t >> 7;
    float a = 0.f;
    #pragma unroll 4
    for (int l = half * 256; l < half * 256 + 256; ++l)
      a += ol[l] * wuv[((size_t)l * NH + h) * NDV + v];
    red[half][v] = a;
  }
  __syncthreads();
  if (t < NDV) ov[(size_t)bh * NDV + t] = red[0][t] + red[1][t];
}

// ---------------- Kernel 4: GEMM partials over n-chunks of 64
__global__ void k_gemm_part(const float* __restrict__ ov,
                            const float* __restrict__ wo,
                            float* __restrict__ gp) {
  int mc = blockIdx.x;  // 0..7
  int ns = blockIdx.y;  // 0..NS2-1
  __shared__ float oc[NB * 64];
  int t = threadIdx.x;
  for (int i = t; i < NB * 64; i += 256) {
    int b = i >> 6, n = i & 63;
    oc[i] = ov[(size_t)b * NDM + ns * 64 + n];
  }
  __syncthreads();
  float acc[NB];
  #pragma unroll
  for (int b = 0; b < NB; ++b) acc[b] = 0.f;
  int m = mc * 256 + t;
  for (int n = 0; n < 64; ++n) {
    float wv = wo[(size_t)(ns * 64 + n) * NDM + m];
    #pragma unroll
    for (int b = 0; b < NB; ++b) acc[b] += oc[b * 64 + n] * wv;
  }
  #pragma unroll
  for (int b = 0; b < NB; ++b)
    gp[((size_t)ns * NB + b) * NDM + m] = acc[b];
}

// ---------------- Kernel 5: reduce GEMM partials
__global__ void k_reduce(const float* __restrict__ gp, float* __restrict__ out) {
  int g = blockIdx.x * 256 + threadIdx.x;
  float a = 0.f;
  for (int i = 0; i < NS2; ++i)
    a += gp[(size_t)i * (NB * NDM) + g];
  out[g] = a;
}

extern "C" void kernel_launch(void* const* d_in, const int* in_sizes, int n_in,
                              void* d_out, int out_size, void* d_ws, size_t ws_size,
                              hipStream_t stream) {
  const float* q_nope = (const float*)d_in[0];
  const float* q_pe   = (const float*)d_in[1];
  const float* kv_c   = (const float*)d_in[2];
  const float* k_pe   = (const float*)d_in[3];
  const float* W_UK   = (const float*)d_in[4];
  const float* W_UV   = (const float*)d_in[5];
  const float* W_O    = (const float*)d_in[6];
  const int*   topk   = (const int*)d_in[7];
  float* out = (float*)d_out;

  float* ws = (float*)d_ws;
  short* qle = (short*)ws;                               // NB*NH*576 bf16 = 147456 floats-worth
  float* pm   = ws + 147456;                             // NB*NSPLIT*NH = 8192
  float* psum = pm + 8192;                               // 8192
  unsigned short* po = (unsigned short*)(psum + 8192);   // NB*NSPLIT*NH*NL bf16 = 2097152 floats-worth
  float* ov   = psum + 8192 + 2097152;                   // NB*NH*NDV = 65536
  float* gp   = ov + 65536;                              // NS2*NB*NDM = 2097152

  k_qprep<<<NB * NH, 256, 0, stream>>>(q_nope, q_pe, W_UK, qle);
  k_attn<<<dim3(NSPLIT, NB), 256, 0, stream>>>(kv_c, k_pe, topk, qle,
                                               pm, psum, po);
  k_combine<<<NB * NH, 256, 0, stream>>>(pm, psum, po, W_UV, ov);
  k_gemm_part<<<dim3(8, NS2), 256, 0, stream>>>(ov, W_O, gp);
  k_reduce<<<(NB * NDM) / 256, 256, 0, stream>>>(gp, out);
}